// Round 3
// baseline (263.412 us; speedup 1.0000x reference)
//
#include <hip/hip_runtime.h>
#include <math.h>

#define M_ 4
#define B_ 8192
#define C_ 1000
#define LOGC 6.907755278982137f  // ln(1000)

// ---------------------------------------------------------------------------
// Single fused kernel: one block per sample b; wave m (of 4) owns row (m, b).
//  - each wave: float4 loads (row register-resident), shuffle-reduce max,
//    then sum + sumexp  ->  ce[m], ent[m] in LDS
//  - ONE barrier; then EVERY thread recomputes the 4-way argmin from the 8
//    LDS floats (broadcast reads) so no second barrier / s_win publish.
//  - thread 0: writes min_index (as float) and atomicAdd's the per-sample
//    scalar contribution into out[0] (zeroed by a 4-byte memset up front).
//  - winning wave writes its register-held row (oracle_logits): no second
//    HBM read of logits.
// Traffic: 131 MB read + 32.8 MB write  ->  ~26 us floor at 6.3 TB/s.
// ---------------------------------------------------------------------------
__global__ __launch_bounds__(256) void fused_kernel(
    const float* __restrict__ logits, const int* __restrict__ targets,
    float* __restrict__ out) {
  const int b = blockIdx.x;
  const int m = threadIdx.x >> 6;  // wave index == model index
  const int lane = threadIdx.x & 63;

  const float* rowp = logits + ((size_t)m * B_ + b) * C_;
  const float4* p = (const float4*)rowp;  // 1000 % 4 == 0, 16B-aligned

  float4 v[4];
#pragma unroll
  for (int k = 0; k < 4; ++k) {
    const int idx = lane + 64 * k;
    if (k < 3 || idx < 250) {
      v[k] = p[idx];
    } else {
      v[k] = make_float4(0.f, 0.f, 0.f, 0.f);
    }
  }
  const int nvalid = (lane < 58) ? 4 : 3;  // lane+192 < 250 iff lane < 58

  // row max
  float lmax = -INFINITY;
#pragma unroll
  for (int k = 0; k < 4; ++k)
    if (k < nvalid)
      lmax = fmaxf(lmax, fmaxf(fmaxf(v[k].x, v[k].y), fmaxf(v[k].z, v[k].w)));
#pragma unroll
  for (int off = 32; off; off >>= 1) lmax = fmaxf(lmax, __shfl_xor(lmax, off));

  // sum(x), sum(exp(x - max))
  float lsum = 0.f, lexp = 0.f;
#pragma unroll
  for (int k = 0; k < 4; ++k) {
    if (k < nvalid) {
      lsum += (v[k].x + v[k].y) + (v[k].z + v[k].w);
      lexp += __expf(v[k].x - lmax) + __expf(v[k].y - lmax) +
              __expf(v[k].z - lmax) + __expf(v[k].w - lmax);
    }
  }
#pragma unroll
  for (int off = 32; off; off >>= 1) {
    lsum += __shfl_xor(lsum, off);
    lexp += __shfl_xor(lexp, off);
  }

  __shared__ float s_ce[M_], s_ent[M_];
  if (lane == 0) {
    const float lse = lmax + __logf(lexp);
    s_ce[m] = lse - rowp[targets[b]];              // -logp[target]
    s_ent[m] = lse - lsum * (1.0f / C_) - LOGC;    // -log C - mean(logp)
  }
  __syncthreads();

  // every thread: argmin over M=4 losses (broadcast LDS reads, no conflicts)
  const float tot = (s_ent[0] + s_ent[1]) + (s_ent[2] + s_ent[3]);
  float best = s_ce[0] + (tot - s_ent[0]);
  int bi = 0;
#pragma unroll
  for (int j = 1; j < M_; ++j) {
    const float l = s_ce[j] + (tot - s_ent[j]);
    if (l < best) { best = l; bi = j; }  // strict <: first-min tie-break
  }

  if (threadIdx.x == 0) {
    out[1 + (size_t)B_ * C_ + b] = (float)bi;  // min_index as float
    atomicAdd(out, (s_ce[bi] - s_ent[bi] + tot) * (1.0f / B_));
  }

  // winning wave writes its register-held row (oracle_logits). Scalar dword
  // stores: region starts at out+1 (4B-misaligned for float4); 64 contiguous
  // lanes per store coalesce to full cache lines anyway.
  if (m == bi) {
    float* dst = out + 1 + (size_t)b * C_;
#pragma unroll
    for (int k = 0; k < 4; ++k) {
      const int idx = lane + 64 * k;
      if (k < 3 || idx < 250) {
        const int e = 4 * idx;
        dst[e + 0] = v[k].x;
        dst[e + 1] = v[k].y;
        dst[e + 2] = v[k].z;
        dst[e + 3] = v[k].w;
      }
    }
  }
}

extern "C" void kernel_launch(void* const* d_in, const int* in_sizes, int n_in,
                              void* d_out, int out_size, void* d_ws,
                              size_t ws_size, hipStream_t stream) {
  const float* logits = (const float*)d_in[0];
  const int* targets = (const int*)d_in[1];
  float* out = (float*)d_out;

  hipMemsetAsync(d_out, 0, sizeof(float), stream);  // zero scalar accumulator
  fused_kernel<<<B_, 256, 0, stream>>>(logits, targets, out);
}

// Round 5
// 188.548 us; speedup vs baseline: 1.3971x; 1.3971x over previous
//
#include <hip/hip_runtime.h>
#include <math.h>

#define M_ 4
#define B_ 8192
#define C_ 1000
#define LOGC 6.907755278982137f  // ln(1000)

// clang native vector type: required for __builtin_nontemporal_load/store
// (HIP's float4 is a struct and is rejected by the builtin — R4 lesson).
typedef float vf4 __attribute__((ext_vector_type(4)));

// ---------------------------------------------------------------------------
// Fused kernel: one block per sample b; wave m (of 4) owns row (m, b).
//  - wave: nontemporal float4 loads (row register-resident), shuffle-reduce
//    max, then sum + sumexp  ->  ce[m], ent[m] in LDS.
//  - target logit comes from REGISTERS via __shfl broadcast (no dependent
//    global re-read on the critical path to the barrier).
//  - one barrier; every thread recomputes the 4-way argmin from 8 LDS floats.
//  - thread 0 writes min_index (as float) + per-sample scalar partial to ws.
//    NO same-address atomics (R3 lesson: 8192 same-line atomicAdds serialize
//    at the L2 channel, ~15 ns each = +65 us).
//  - winning wave streams its register-held row to out (oracle_logits).
// Traffic: 131 MB read + 32.8 MB write  ->  ~26 us floor at 6.3 TB/s.
// ---------------------------------------------------------------------------
__global__ __launch_bounds__(256) void fused_kernel(
    const float* __restrict__ logits, const int* __restrict__ targets,
    float* __restrict__ out, float* __restrict__ partials) {
  const int b = blockIdx.x;
  const int m = threadIdx.x >> 6;  // wave index == model index
  const int lane = threadIdx.x & 63;

  const int tgt = targets[b];  // issue early; independent of row loads

  const float* rowp = logits + ((size_t)m * B_ + b) * C_;
  const vf4* p = (const vf4*)rowp;  // 1000 % 4 == 0, 16B-aligned

  vf4 v[4];
#pragma unroll
  for (int k = 0; k < 4; ++k) {
    const int idx = lane + 64 * k;
    if (k < 3 || idx < 250) {
      v[k] = __builtin_nontemporal_load(p + idx);  // streaming, no reuse
    } else {
      v[k] = (vf4){0.f, 0.f, 0.f, 0.f};
    }
  }
  const int nvalid = (lane < 58) ? 4 : 3;  // lane+192 < 250 iff lane < 58

  // target logit from registers: element tgt lives in float4 q = tgt>>2,
  // owned by lane (q & 63) at register slot (q >> 6), component (tgt & 3).
  // q, comp, owner are wave-uniform; owner lane for slot 3 is < 58 (valid).
  const int q = tgt >> 2, comp = tgt & 3, owner = q & 63, kq = q >> 6;
  float ck[4];
#pragma unroll
  for (int k = 0; k < 4; ++k)
    ck[k] = (comp == 0) ? v[k].x
          : (comp == 1) ? v[k].y
          : (comp == 2) ? v[k].z : v[k].w;
  const float cand = (kq == 0) ? ck[0] : (kq == 1) ? ck[1]
                   : (kq == 2) ? ck[2] : ck[3];
  const float tval = __shfl(cand, owner);

  // row max
  float lmax = -INFINITY;
#pragma unroll
  for (int k = 0; k < 4; ++k)
    if (k < nvalid)
      lmax = fmaxf(lmax, fmaxf(fmaxf(v[k].x, v[k].y), fmaxf(v[k].z, v[k].w)));
#pragma unroll
  for (int off = 32; off; off >>= 1) lmax = fmaxf(lmax, __shfl_xor(lmax, off));

  // sum(x), sum(exp(x - max))
  float lsum = 0.f, lexp = 0.f;
#pragma unroll
  for (int k = 0; k < 4; ++k) {
    if (k < nvalid) {
      lsum += (v[k].x + v[k].y) + (v[k].z + v[k].w);
      lexp += __expf(v[k].x - lmax) + __expf(v[k].y - lmax) +
              __expf(v[k].z - lmax) + __expf(v[k].w - lmax);
    }
  }
#pragma unroll
  for (int off = 32; off; off >>= 1) {
    lsum += __shfl_xor(lsum, off);
    lexp += __shfl_xor(lexp, off);
  }

  __shared__ float s_ce[M_], s_ent[M_];
  if (lane == 0) {
    const float lse = lmax + __logf(lexp);
    s_ce[m] = lse - tval;                          // -logp[target]
    s_ent[m] = lse - lsum * (1.0f / C_) - LOGC;    // -log C - mean(logp)
  }
  __syncthreads();

  // every thread: argmin over M=4 losses (broadcast LDS reads)
  const float tot = (s_ent[0] + s_ent[1]) + (s_ent[2] + s_ent[3]);
  float best = s_ce[0] + (tot - s_ent[0]);
  int bi = 0;
#pragma unroll
  for (int j = 1; j < M_; ++j) {
    const float l = s_ce[j] + (tot - s_ent[j]);
    if (l < best) { best = l; bi = j; }  // strict <: first-min tie-break
  }

  if (threadIdx.x == 0) {
    out[1 + (size_t)B_ * C_ + b] = (float)bi;                  // min_index
    partials[b] = (s_ce[bi] - s_ent[bi] + tot) * (1.0f / B_);  // scalar part
  }

  // winning wave streams its register-held row (oracle_logits). Scalar dword
  // stores: region starts at out+1 (4B-misaligned for float4); 64 contiguous
  // lanes per store still coalesce to full lines.
  if (m == bi) {
    float* dst = out + 1 + (size_t)b * C_;
#pragma unroll
    for (int k = 0; k < 4; ++k) {
      const int idx = lane + 64 * k;
      if (k < 3 || idx < 250) {
        const int e = 4 * idx;
        __builtin_nontemporal_store(v[k].x, dst + e + 0);
        __builtin_nontemporal_store(v[k].y, dst + e + 1);
        __builtin_nontemporal_store(v[k].z, dst + e + 2);
        __builtin_nontemporal_store(v[k].w, dst + e + 3);
      }
    }
  }
}

// ---------------------------------------------------------------------------
// Final reduce: sum B partials -> out[0]. Single block, plain store; no
// memset, no atomics, deterministic.
// ---------------------------------------------------------------------------
__global__ __launch_bounds__(1024) void reduce_kernel(
    const float* __restrict__ partials, float* __restrict__ out) {
  const float4* p4 = (const float4*)partials;  // B/4 = 2048 float4
  float s = 0.f;
#pragma unroll
  for (int k = 0; k < 2; ++k) {
    const float4 v = p4[threadIdx.x + 1024 * k];
    s += (v.x + v.y) + (v.z + v.w);
  }
#pragma unroll
  for (int off = 32; off; off >>= 1) s += __shfl_xor(s, off);

  __shared__ float red[16];
  if ((threadIdx.x & 63) == 0) red[threadIdx.x >> 6] = s;
  __syncthreads();
  if (threadIdx.x < 16) {
    float t = red[threadIdx.x];
#pragma unroll
    for (int off = 8; off; off >>= 1) t += __shfl_xor(t, off, 16);
    if (threadIdx.x == 0) out[0] = t;
  }
}

extern "C" void kernel_launch(void* const* d_in, const int* in_sizes, int n_in,
                              void* d_out, int out_size, void* d_ws,
                              size_t ws_size, hipStream_t stream) {
  const float* logits = (const float*)d_in[0];
  const int* targets = (const int*)d_in[1];
  float* out = (float*)d_out;
  float* partials = (float*)d_ws;  // B floats

  fused_kernel<<<B_, 256, 0, stream>>>(logits, targets, out, partials);
  reduce_kernel<<<1, 1024, 0, stream>>>(partials, out);
}